// Round 17
// baseline (51.122 us; speedup 1.0000x reference)
//
#include <hip/hip_runtime.h>
#include <math.h>

// Full stable softplus [2 trans]
__device__ __forceinline__ float spf(float x) {
    float a = fabsf(x);
    float e = __expf(-a);
    float l = __logf(1.0f + e);
    return fmaxf(x, 0.0f) + l;
}
// Naive softplus [2 trans], safe for x in (-87, 88)
__device__ __forceinline__ float spn(float x) {
    return __logf(1.0f + __expf(x));
}
// Quick softplus for z > 2: z + e^-z, |err| <= 0.0084 [1 trans]
__device__ __forceinline__ float spq(float x) {
    return x + __expf(-x);
}
__device__ __forceinline__ float sigm(float x) {
    return 1.0f / (1.0f + __expf(-x));
}

// Setup: e_id, h_s, folded epilogue consts. H = h_s*I exactly (see R0 analysis):
// at F=I, dX/dF = [2I, I, -I, 4I] with exact-zero off-diagonals, so
// correction = h_s * tr(E) = h_s*(trC-3)/2, res = e + c0 + c1*trC.
__global__ void setup_kernel(const float* __restrict__ W0, const float* __restrict__ b0,
                             const float* __restrict__ Wh, const float* __restrict__ bh,
                             const float* __restrict__ Wf, const float* __restrict__ bf,
                             float* __restrict__ ws) {
    if (threadIdx.x != 0 || blockIdx.x != 0) return;
    float x[4] = {3.f, 1.f, -1.f, 3.f};
    float zin[5], h[5], zh[4][5];
    for (int j = 0; j < 5; ++j) {
        float z = b0[j];
        for (int m = 0; m < 4; ++m) z += x[m] * W0[m * 5 + j];
        zin[j] = z; h[j] = spf(z);
    }
    for (int i = 0; i < 4; ++i) {
        float hn[5];
        for (int j = 0; j < 5; ++j) {
            float z = bh[i * 5 + j];
            for (int k = 0; k < 5; ++k) z += h[k] * Wh[i * 25 + k * 5 + j];
            zh[i][j] = z; hn[j] = spf(z);
        }
        for (int j = 0; j < 5; ++j) h[j] = hn[j];
    }
    float zf = bf[0];
    for (int k = 0; k < 5; ++k) zf += h[k] * Wf[k];
    float e_id = spf(zf);
    float d[5];
    float szf = sigm(zf);
    for (int k = 0; k < 5; ++k) d[k] = Wf[k] * szf;
    for (int i = 3; i >= 0; --i) {
        float dz[5];
        for (int j = 0; j < 5; ++j) dz[j] = d[j] * sigm(zh[i][j]);
        for (int k = 0; k < 5; ++k) {
            float acc = 0.f;
            for (int j = 0; j < 5; ++j) acc += Wh[i * 25 + k * 5 + j] * dz[j];
            d[k] = acc;
        }
    }
    float dz0[5], g[4];
    for (int j = 0; j < 5; ++j) dz0[j] = d[j] * sigm(zin[j]);
    for (int m = 0; m < 4; ++m) {
        float acc = 0.f;
        for (int j = 0; j < 5; ++j) acc += W0[m * 5 + j] * dz0[j];
        g[m] = acc;
    }
    float h_s = -(2.f * g[0] + g[1] - g[2] + 4.f * g[3]);
    float c1 = 0.5f * h_s;
    ws[0] = e_id;
    ws[1] = h_s;
    ws[2] = c1;
    ws[3] = -e_id - 3.0f * c1;     // c0
}

// 1 sample/thread. Smallest possible body (~35 VGPR), 65536 waves, finest
// votes (64 samples) -> fast paths fire most often. No tail path (n = #threads).
__global__ __launch_bounds__(256, 8) void main_kernel(
        const float* __restrict__ F,
        const float* __restrict__ W0, const float* __restrict__ b0,
        const float* __restrict__ Wh, const float* __restrict__ bh,
        const float* __restrict__ Wf, const float* __restrict__ bf,
        const float* __restrict__ cs,   // [e_id, h_s, c1, c0]
        float* __restrict__ out, int n) {
    const long long i = (long long)blockIdx.x * blockDim.x + threadIdx.x;
    if (i >= n) return;
    const float* f = F + i * 9;
    float f0=f[0], f1=f[1], f2=f[2], f3=f[3], f4=f[4], f5=f[5], f6=f[6], f7=f[7], f8=f[8];

    // invariants; I2 via principal 2x2 minors
    float c00=f0*f0+f3*f3+f6*f6, c11=f1*f1+f4*f4+f7*f7, c22=f2*f2+f5*f5+f8*f8;
    float c01=f0*f1+f3*f4+f6*f7, c02=f0*f2+f3*f5+f6*f8, c12=f1*f2+f4*f5+f7*f8;
    float trC = c00+c11+c22;
    float I2 = fmaf(c00, c11, -(c01*c01)) + fmaf(c00, c22, -(c02*c02)) + fmaf(c11, c22, -(c12*c12));
    float t0 = fmaf(f4, f8, -(f5*f7));
    float t1 = fmaf(f3, f8, -(f5*f6));
    float t2 = fmaf(f3, f7, -(f4*f6));
    float J = fmaf(f2, t2, fmaf(-f1, t1, f0*t0));

    // fold epilogue: res = e + tail
    const float c1 = cs[2], c0 = cs[3];
    float tail = fmaf(trC, c1, c0);

    // input layer (fold J and -J rows)
    float h0,h1,h2,h3,h4;
    {
        float z0 = fmaf(I2, W0[15], fmaf(J, W0[5]-W0[10], fmaf(trC, W0[0], b0[0])));
        float z1 = fmaf(I2, W0[16], fmaf(J, W0[6]-W0[11], fmaf(trC, W0[1], b0[1])));
        float z2 = fmaf(I2, W0[17], fmaf(J, W0[7]-W0[12], fmaf(trC, W0[2], b0[2])));
        float z3 = fmaf(I2, W0[18], fmaf(J, W0[8]-W0[13], fmaf(trC, W0[3], b0[3])));
        float z4 = fmaf(I2, W0[19], fmaf(J, W0[9]-W0[14], fmaf(trC, W0[4], b0[4])));
        float mm = fminf(fminf(fminf(z0,z1),fminf(z2,z3)),z4);
        if (__all(mm > 3.0f)) {
            h0=spq(z0); h1=spq(z1); h2=spq(z2); h3=spq(z3); h4=spq(z4);
        } else {
            h0=spn(z0); h1=spn(z1); h2=spn(z2); h3=spn(z3); h4=spn(z4);
        }
    }
    // hidden layers 1..4 with cascaded activation
    #pragma unroll
    for (int l = 0; l < 4; ++l) {
        const float* W = Wh + l*25;
        const float* B = bh + l*5;
        float z0 = B[0], z1 = B[1], z2 = B[2], z3 = B[3], z4 = B[4];
        z0 = fmaf(h0, W[0],  z0); z1 = fmaf(h0, W[1],  z1); z2 = fmaf(h0, W[2],  z2); z3 = fmaf(h0, W[3],  z3); z4 = fmaf(h0, W[4],  z4);
        z0 = fmaf(h1, W[5],  z0); z1 = fmaf(h1, W[6],  z1); z2 = fmaf(h1, W[7],  z2); z3 = fmaf(h1, W[8],  z3); z4 = fmaf(h1, W[9],  z4);
        z0 = fmaf(h2, W[10], z0); z1 = fmaf(h2, W[11], z1); z2 = fmaf(h2, W[12], z2); z3 = fmaf(h2, W[13], z3); z4 = fmaf(h2, W[14], z4);
        z0 = fmaf(h3, W[15], z0); z1 = fmaf(h3, W[16], z1); z2 = fmaf(h3, W[17], z2); z3 = fmaf(h3, W[18], z3); z4 = fmaf(h3, W[19], z4);
        z0 = fmaf(h4, W[20], z0); z1 = fmaf(h4, W[21], z1); z2 = fmaf(h4, W[22], z2); z3 = fmaf(h4, W[23], z3); z4 = fmaf(h4, W[24], z4);
        float mm = fminf(fminf(fminf(z0,z1),fminf(z2,z3)),z4);
        if (__all(mm > 17.0f)) {
            h0=z0; h1=z1; h2=z2; h3=z3; h4=z4;          // identity, exact in fp32
        } else if (__all(mm > 2.0f)) {
            h0=spq(z0); h1=spq(z1); h2=spq(z2); h3=spq(z3); h4=spq(z4);
        } else {
            h0=spf(z0); h1=spf(z1); h2=spf(z2); h3=spf(z3); h4=spf(z4);
        }
    }
    float zf = bf[0];
    zf = fmaf(h0, Wf[0], zf);
    zf = fmaf(h1, Wf[1], zf);
    zf = fmaf(h2, Wf[2], zf);
    zf = fmaf(h3, Wf[3], zf);
    zf = fmaf(h4, Wf[4], zf);
    float e;
    if (__all(zf > 17.0f)) e = zf;
    else if (__all(zf > 2.0f)) e = spq(zf);
    else e = spf(zf);

    out[i] = e + tail;
}

extern "C" void kernel_launch(void* const* d_in, const int* in_sizes, int n_in,
                              void* d_out, int out_size, void* d_ws, size_t ws_size,
                              hipStream_t stream) {
    const float* F  = (const float*)d_in[0];
    const float* W0 = (const float*)d_in[1];
    const float* b0 = (const float*)d_in[2];
    const float* Wh = (const float*)d_in[3];
    const float* bh = (const float*)d_in[4];
    const float* Wf = (const float*)d_in[5];
    const float* bf = (const float*)d_in[6];
    float* out = (float*)d_out;
    float* ws  = (float*)d_ws;
    int n = in_sizes[0] / 9;
    setup_kernel<<<1, 64, 0, stream>>>(W0, b0, Wh, bh, Wf, bf, ws);
    int block = 256;
    int grid = (int)(((long long)n + block - 1) / block);
    if (grid < 1) grid = 1;
    main_kernel<<<grid, block, 0, stream>>>(F, W0, b0, Wh, bh, Wf, bf, ws, out, n);
}

// Round 18
// 48.748 us; speedup vs baseline: 1.0487x; 1.0487x over previous
//
#include <hip/hip_runtime.h>
#include <math.h>

typedef float v2 __attribute__((ext_vector_type(2)));

// Full stable softplus [2 trans]
__device__ __forceinline__ float spf(float x) {
    float a = fabsf(x);
    float e = __expf(-a);
    float l = __logf(1.0f + e);
    return fmaxf(x, 0.0f) + l;
}
// Naive softplus [2 trans], safe for x in (-87, 88)
__device__ __forceinline__ float spn(float x) {
    return __logf(1.0f + __expf(x));
}
__device__ __forceinline__ float sigm(float x) {
    return 1.0f / (1.0f + __expf(-x));
}
__device__ __forceinline__ v2 splat2(float s) { v2 r; r.x=s; r.y=s; return r; }
__device__ __forceinline__ v2 sp2(v2 x)  { v2 r; r.x=spf(x.x); r.y=spf(x.y); return r; }
__device__ __forceinline__ v2 sp2n(v2 x) { v2 r; r.x=spn(x.x); r.y=spn(x.y); return r; }
// Quick softplus for z > 2: z + e^-z, |err| <= 0.0084 [1 trans]
__device__ __forceinline__ v2 spq2(v2 x) {
    v2 r;
    r.x = x.x + __expf(-x.x);
    r.y = x.y + __expf(-x.y);
    return r;
}
__device__ __forceinline__ v2 vfma2(v2 a, float b, v2 c) {
    v2 bb; bb.x = b; bb.y = b;
    return __builtin_elementwise_fma(a, bb, c);
}
__device__ __forceinline__ v2 vmin2(v2 a, v2 b) {
    v2 r; r.x=fminf(a.x,b.x); r.y=fminf(a.y,b.y); return r;
}

// Setup: e_id, h_s, folded epilogue consts. H = h_s*I exactly (see R0 analysis).
__global__ void setup_kernel(const float* __restrict__ W0, const float* __restrict__ b0,
                             const float* __restrict__ Wh, const float* __restrict__ bh,
                             const float* __restrict__ Wf, const float* __restrict__ bf,
                             float* __restrict__ ws) {
    if (threadIdx.x != 0 || blockIdx.x != 0) return;
    float x[4] = {3.f, 1.f, -1.f, 3.f};
    float zin[5], h[5], zh[4][5];
    for (int j = 0; j < 5; ++j) {
        float z = b0[j];
        for (int m = 0; m < 4; ++m) z += x[m] * W0[m * 5 + j];
        zin[j] = z; h[j] = spf(z);
    }
    for (int i = 0; i < 4; ++i) {
        float hn[5];
        for (int j = 0; j < 5; ++j) {
            float z = bh[i * 5 + j];
            for (int k = 0; k < 5; ++k) z += h[k] * Wh[i * 25 + k * 5 + j];
            zh[i][j] = z; hn[j] = spf(z);
        }
        for (int j = 0; j < 5; ++j) h[j] = hn[j];
    }
    float zf = bf[0];
    for (int k = 0; k < 5; ++k) zf += h[k] * Wf[k];
    float e_id = spf(zf);
    float d[5];
    float szf = sigm(zf);
    for (int k = 0; k < 5; ++k) d[k] = Wf[k] * szf;
    for (int i = 3; i >= 0; --i) {
        float dz[5];
        for (int j = 0; j < 5; ++j) dz[j] = d[j] * sigm(zh[i][j]);
        for (int k = 0; k < 5; ++k) {
            float acc = 0.f;
            for (int j = 0; j < 5; ++j) acc += Wh[i * 25 + k * 5 + j] * dz[j];
            d[k] = acc;
        }
    }
    float dz0[5], g[4];
    for (int j = 0; j < 5; ++j) dz0[j] = d[j] * sigm(zin[j]);
    for (int m = 0; m < 4; ++m) {
        float acc = 0.f;
        for (int j = 0; j < 5; ++j) acc += W0[m * 5 + j] * dz0[j];
        g[m] = acc;
    }
    float h_s = -(2.f * g[0] + g[1] - g[2] + 4.f * g[3]);
    float c1 = 0.5f * h_s;
    ws[0] = e_id;
    ws[1] = h_s;
    ws[2] = c1;                    // res = e + c0 + c1*trC
    ws[3] = -e_id - 3.0f * c1;     // c0
}

__device__ __forceinline__ float scalar_sample(const float* f,
        const float* W0, const float* b0, const float* Wh, const float* bh,
        const float* Wf, const float* bf, float e_id, float h_s) {
    float f0=f[0],f1=f[1],f2=f[2],f3=f[3],f4=f[4],f5=f[5],f6=f[6],f7=f[7],f8=f[8];
    float c00=f0*f0+f3*f3+f6*f6, c11=f1*f1+f4*f4+f7*f7, c22=f2*f2+f5*f5+f8*f8;
    float c01=f0*f1+f3*f4+f6*f7, c02=f0*f2+f3*f5+f6*f8, c12=f1*f2+f4*f5+f7*f8;
    float trC=c00+c11+c22;
    float trC2=c00*c00+c11*c11+c22*c22+2.f*(c01*c01+c02*c02+c12*c12);
    float I2=0.5f*(trC*trC-trC2);
    float J=f0*(f4*f8-f5*f7)-f1*(f3*f8-f5*f6)+f2*(f3*f7-f4*f6);
    float h[5];
    for (int j=0;j<5;++j)
        h[j]=spf(b0[j]+trC*W0[j]+J*(W0[5+j]-W0[10+j])+I2*W0[15+j]);
    for (int l=0;l<4;++l){
        float hn[5];
        for (int j=0;j<5;++j){
            float z=bh[l*5+j];
            for (int k=0;k<5;++k) z=fmaf(h[k],Wh[l*25+k*5+j],z);
            hn[j]=spf(z);
        }
        for (int j=0;j<5;++j) h[j]=hn[j];
    }
    float zf=bf[0];
    for (int k=0;k<5;++k) zf=fmaf(h[k],Wf[k],zf);
    return (spf(zf)-e_id)+h_s*0.5f*(trC-3.0f);
}

// Invariants; I2 via principal 2x2 minors.
__device__ __forceinline__ void inv9(
        float f0, float f1, float f2, float f3, float f4,
        float f5, float f6, float f7, float f8,
        float& tc_o, float& J_o, float& I2_o) {
    float c00=f0*f0+f3*f3+f6*f6, c11=f1*f1+f4*f4+f7*f7, c22=f2*f2+f5*f5+f8*f8;
    float c01=f0*f1+f3*f4+f6*f7, c02=f0*f2+f3*f5+f6*f8, c12=f1*f2+f4*f5+f7*f8;
    tc_o = c00+c11+c22;
    float m0 = fmaf(c00, c11, -(c01*c01));
    float m1 = fmaf(c00, c22, -(c02*c02));
    float m2 = fmaf(c11, c22, -(c12*c12));
    I2_o = m0 + m1 + m2;
    float t0 = fmaf(f4, f8, -(f5*f7));
    float t1 = fmaf(f3, f8, -(f5*f6));
    float t2 = fmaf(f3, f7, -(f4*f6));
    J_o = fmaf(f2, t2, fmaf(-f1, t1, f0*t0));
}

// 2 samples/thread: best point on the body-size/occupancy tradeoff (R15).
// 32768 waves, VGPR ~55 -> 8 waves/SIMD. Loads: 9 x dwordx2 (8B-aligned).
__global__ __launch_bounds__(256, 8) void main_kernel(
        const float* __restrict__ F,
        const float* __restrict__ W0, const float* __restrict__ b0,
        const float* __restrict__ Wh, const float* __restrict__ bh,
        const float* __restrict__ Wf, const float* __restrict__ bf,
        const float* __restrict__ cs,   // [e_id, h_s, c1, c0]
        float* __restrict__ out, int n) {
    const long long t = (long long)blockIdx.x * blockDim.x + threadIdx.x;
    const long long i0 = t * 2;
    if (i0 >= n) return;

    if (i0 + 2 <= (long long)n) {
        const v2* p = (const v2*)(F + i0 * 9);   // 8B-aligned
        v2 e0=p[0],e1=p[1],e2=p[2],e3=p[3],e4=p[4],e5=p[5],e6=p[6],e7=p[7],e8=p[8];

        float tcA,jA,qA, tcB,jB,qB;
        inv9(e0.x,e0.y,e1.x,e1.y,e2.x,e2.y,e3.x,e3.y,e4.x, tcA,jA,qA);
        inv9(e4.y,e5.x,e5.y,e6.x,e6.y,e7.x,e7.y,e8.x,e8.y, tcB,jB,qB);
        v2 trC, J, I2;
        trC.x=tcA; trC.y=tcB;
        J.x=jA;   J.y=jB;
        I2.x=qA;  I2.y=qB;

        // fold epilogue now: res = e + tail; trC dies here
        const float c1 = cs[2], c0 = cs[3];
        v2 tail = vfma2(trC, c1, splat2(c0));

        // input layer (fold J and -J rows), vote: >3 -> spq (1 trans), else naive
        v2 h0,h1,h2,h3,h4;
        {
            v2 z0,z1,z2,z3,z4;
            #define L0Z(J_, Z_) \
                Z_ = splat2(b0[J_]); \
                Z_ = vfma2(trC, W0[J_], Z_); \
                Z_ = vfma2(J, W0[5+J_]-W0[10+J_], Z_); \
                Z_ = vfma2(I2, W0[15+J_], Z_);
            L0Z(0,z0) L0Z(1,z1) L0Z(2,z2) L0Z(3,z3) L0Z(4,z4)
            #undef L0Z
            v2 m = vmin2(vmin2(vmin2(z0,z1),vmin2(z2,z3)),z4);
            float mm = fminf(m.x,m.y);
            if (__all(mm > 3.0f)) {
                h0=spq2(z0); h1=spq2(z1); h2=spq2(z2); h3=spq2(z3); h4=spq2(z4);
            } else {
                h0=sp2n(z0); h1=sp2n(z1); h2=sp2n(z2); h3=sp2n(z3); h4=sp2n(z4);
            }
        }
        // hidden layers 1..4 with cascaded activation
        #pragma unroll
        for (int l = 0; l < 4; ++l) {
            v2 z0,z1,z2,z3,z4;
            #define ZJ(J_, Z_) \
                Z_ = splat2(bh[l*5+J_]); \
                Z_ = vfma2(h0, Wh[l*25+0*5+J_], Z_); \
                Z_ = vfma2(h1, Wh[l*25+1*5+J_], Z_); \
                Z_ = vfma2(h2, Wh[l*25+2*5+J_], Z_); \
                Z_ = vfma2(h3, Wh[l*25+3*5+J_], Z_); \
                Z_ = vfma2(h4, Wh[l*25+4*5+J_], Z_);
            ZJ(0,z0) ZJ(1,z1) ZJ(2,z2) ZJ(3,z3) ZJ(4,z4)
            #undef ZJ
            v2 m = vmin2(vmin2(vmin2(z0,z1),vmin2(z2,z3)),z4);
            float mm = fminf(m.x,m.y);
            if (__all(mm > 17.0f)) {
                h0=z0; h1=z1; h2=z2; h3=z3; h4=z4;          // identity, exact
            } else if (__all(mm > 2.0f)) {
                h0=spq2(z0); h1=spq2(z1); h2=spq2(z2); h3=spq2(z3); h4=spq2(z4);
            } else {
                h0=sp2(z0); h1=sp2(z1); h2=sp2(z2); h3=sp2(z3); h4=sp2(z4);
            }
        }
        v2 zf = splat2(bf[0]);
        zf = vfma2(h0, Wf[0], zf);
        zf = vfma2(h1, Wf[1], zf);
        zf = vfma2(h2, Wf[2], zf);
        zf = vfma2(h3, Wf[3], zf);
        zf = vfma2(h4, Wf[4], zf);
        float mf = fminf(zf.x, zf.y);
        v2 e;
        if (__all(mf > 17.0f)) e = zf;
        else if (__all(mf > 2.0f)) e = spq2(zf);
        else e = sp2(zf);

        *(v2*)(out + i0) = e + tail;
    } else {
        const float eid = cs[0], hs = cs[1];
        out[i0] = scalar_sample(F + (size_t)i0 * 9, W0, b0, Wh, bh, Wf, bf, eid, hs);
    }
}

extern "C" void kernel_launch(void* const* d_in, const int* in_sizes, int n_in,
                              void* d_out, int out_size, void* d_ws, size_t ws_size,
                              hipStream_t stream) {
    const float* F  = (const float*)d_in[0];
    const float* W0 = (const float*)d_in[1];
    const float* b0 = (const float*)d_in[2];
    const float* Wh = (const float*)d_in[3];
    const float* bh = (const float*)d_in[4];
    const float* Wf = (const float*)d_in[5];
    const float* bf = (const float*)d_in[6];
    float* out = (float*)d_out;
    float* ws  = (float*)d_ws;
    int n = in_sizes[0] / 9;
    setup_kernel<<<1, 64, 0, stream>>>(W0, b0, Wh, bh, Wf, bf, ws);
    int block = 256;
    long long threads = ((long long)n + 1) / 2;
    int grid = (int)((threads + block - 1) / block);
    if (grid < 1) grid = 1;
    main_kernel<<<grid, block, 0, stream>>>(F, W0, b0, Wh, bh, Wf, bf, ws, out, n);
}